// Round 1
// baseline (298.694 us; speedup 1.0000x reference)
//
#include <hip/hip_runtime.h>

typedef unsigned short u16;
typedef _Float16 f16;
typedef __attribute__((ext_vector_type(8))) _Float16 f16x8;
typedef __attribute__((ext_vector_type(4))) _Float16 f16x4;
typedef __attribute__((ext_vector_type(4))) float f32x4;

#define MFMA16(a, b, c) __builtin_amdgcn_mfma_f32_16x16x32_f16((a), (b), (c), 0, 0, 0)

// async global->LDS, 16B per lane. LDS pointer must be WAVE-UNIFORM base;
// HW scatters lane i's 16B to base + i*16 (guide §5, m97/m104).
__device__ __forceinline__ void gld_lds16(const void* g, void* l) {
  __builtin_amdgcn_global_load_lds(
      (__attribute__((address_space(1))) void*)const_cast<void*>(g),
      (__attribute__((address_space(3))) void*)l, 16, 0, 0);
}

__device__ __forceinline__ f16x8 ld8(const f16* p) { return *(const f16x8*)p; }

// ---------------- fp32 -> fp16 elementwise (Q,K,V), grid.z selects tensor ----
__global__ __launch_bounds__(256) void cvt_x_kernel(
    const float* __restrict__ Q, const float* __restrict__ K, const float* __restrict__ V,
    f16* __restrict__ oq, f16* __restrict__ ok, f16* __restrict__ ov) {
  const float* src = blockIdx.z == 0 ? Q : (blockIdx.z == 1 ? K : V);
  f16* dst = blockIdx.z == 0 ? oq : (blockIdx.z == 1 ? ok : ov);
  size_t i = ((size_t)blockIdx.x * 256 + threadIdx.x) * 4;
  float4 f = *(const float4*)(src + i);
  f16x4 o4;
  o4.x = (f16)f.x; o4.y = (f16)f.y; o4.z = (f16)f.z; o4.w = (f16)f.w;
  *(f16x4*)(dst + i) = o4;
}

// ---------------- W [K=1024][N=1024] fp32 -> WT [N][K] fp16 ------------------
__global__ __launch_bounds__(256) void cvt_wT_kernel(
    const float* __restrict__ Wq, const float* __restrict__ Wk,
    const float* __restrict__ Wv, const float* __restrict__ Wo,
    f16* __restrict__ Tq, f16* __restrict__ Tk, f16* __restrict__ Tv, f16* __restrict__ To) {
  const int z = blockIdx.z;
  const float* W = z == 0 ? Wq : (z == 1 ? Wk : (z == 2 ? Wv : Wo));
  f16* T = z == 0 ? Tq : (z == 1 ? Tk : (z == 2 ? Tv : To));
  __shared__ float tile[64][65];  // +1 pad: conflict-free transpose read
  const int k0 = blockIdx.x * 64, n0 = blockIdx.y * 64;
  const int tx = threadIdx.x & 63, ty = threadIdx.x >> 6;
#pragma unroll
  for (int rr = 0; rr < 16; ++rr) {
    int r = rr * 4 + ty;
    tile[r][tx] = W[(size_t)(k0 + r) * 1024 + n0 + tx];
  }
  __syncthreads();
#pragma unroll
  for (int rr = 0; rr < 16; ++rr) {
    int nn = rr * 4 + ty;
    T[(size_t)(n0 + nn) * 1024 + k0 + tx] = (f16)tile[tx][nn];
  }
}

// ---------------- GEMM: C[M=4096][N=1024] = A[M][K=1024] * BT[N][K]^T + bias -
// m97 structure: 128x128 tile, BK=32, global_load_lds(16B), 4 waves, each wave
// 64x64 = 4x4 MFMA 16x16x32 tiles. grid.z selects (A,B,bias,C) triple.
template <bool OUTF32>
__global__ __launch_bounds__(256) void gemm_bt_kernel(
    const f16* __restrict__ A0, const f16* __restrict__ A1, const f16* __restrict__ A2,
    const f16* __restrict__ B0, const f16* __restrict__ B1, const f16* __restrict__ B2,
    const float* __restrict__ bias0, const float* __restrict__ bias1, const float* __restrict__ bias2,
    f16* __restrict__ C0, f16* __restrict__ C1, f16* __restrict__ C2,
    float* __restrict__ Cf) {
  const int z = blockIdx.z;
  const f16* A = z == 0 ? A0 : (z == 1 ? A1 : A2);
  const f16* Bt = z == 0 ? B0 : (z == 1 ? B1 : B2);
  const float* bias = z == 0 ? bias0 : (z == 1 ? bias1 : bias2);
  f16* C = z == 0 ? C0 : (z == 1 ? C1 : C2);

  __shared__ alignas(16) f16 lA[128 * 32];
  __shared__ alignas(16) f16 lB[128 * 32];

  const int t = threadIdx.x;
  const int w = t >> 6, lane = t & 63, quad = lane >> 4, l15 = lane & 15;
  const int wm = w >> 1, wn = w & 1;
  const int mbase = blockIdx.x * 128;
  const int nbase = blockIdx.y * 128;

  const f32x4 zero4 = {0.f, 0.f, 0.f, 0.f};
  f32x4 acc[4][4];
#pragma unroll
  for (int mi = 0; mi < 4; ++mi)
#pragma unroll
    for (int ni = 0; ni < 4; ++ni) acc[mi][ni] = zero4;

  const int r = t >> 2;            // 0..63 staging row
  const int koff = (t & 3) * 8;    // 0,8,16,24

  for (int k0 = 0; k0 < 1024; k0 += 32) {
    __syncthreads();
    // stage A[128][32] and BT-tile[128][32], row-major k-contiguous.
    // thread t's 16B lands at LDS byte t*16 (wave-uniform base + lane*16).
    gld_lds16(A + (size_t)(mbase + r) * 1024 + k0 + koff, (char*)lA + w * 1024);
    gld_lds16(A + (size_t)(mbase + 64 + r) * 1024 + k0 + koff, (char*)lA + 4096 + w * 1024);
    gld_lds16(Bt + (size_t)(nbase + r) * 1024 + k0 + koff, (char*)lB + w * 1024);
    gld_lds16(Bt + (size_t)(nbase + 64 + r) * 1024 + k0 + koff, (char*)lB + 4096 + w * 1024);
    __syncthreads();

    f16x8 af[4], bf[4];
#pragma unroll
    for (int mi = 0; mi < 4; ++mi)
      af[mi] = ld8(&lA[(wm * 64 + mi * 16 + l15) * 32 + quad * 8]);
#pragma unroll
    for (int ni = 0; ni < 4; ++ni)
      bf[ni] = ld8(&lB[(wn * 64 + ni * 16 + l15) * 32 + quad * 8]);
#pragma unroll
    for (int mi = 0; mi < 4; ++mi)
#pragma unroll
      for (int ni = 0; ni < 4; ++ni)
        acc[mi][ni] = MFMA16(af[mi], bf[ni], acc[mi][ni]);
  }

  // epilogue. C/D layout: col=lane&15, row=quad*4+reg (m89/m91 verified).
#pragma unroll
  for (int mi = 0; mi < 4; ++mi) {
#pragma unroll
    for (int ni = 0; ni < 4; ++ni) {
#pragma unroll
      for (int rg = 0; rg < 4; ++rg) {
        const int row = mbase + wm * 64 + mi * 16 + quad * 4 + rg;
        const int col = nbase + wn * 64 + ni * 16 + l15;
        const float v = acc[mi][ni][rg] + bias[col];
        if (OUTF32)
          Cf[(size_t)row * 1024 + col] = v;
        else
          C[(size_t)row * 1024 + col] = (f16)v;
      }
    }
  }
}

// ---------------- flash attention with strided mask --------------------------
// grid: (qtile=16, h=16, b=4), block 256 = 4 waves; wave w owns q-rows
// i0+16w..i0+16w+15, all 64 dk dims. Key tiles of 32, causal bound.
__global__ __launch_bounds__(256) void attn_kernel(
    const f16* __restrict__ qp, const f16* __restrict__ kp, const f16* __restrict__ vp,
    f16* __restrict__ ao) {
  const int qt = blockIdx.x, h = blockIdx.y, b = blockIdx.z;
  const int i0 = qt * 64;
  const int t = threadIdx.x;
  const int w = t >> 6, lane = t & 63, quad = lane >> 4, l15 = lane & 15;

  __shared__ alignas(16) f16 lk[32 * 64];      // k-tile [key][dk]
  __shared__ alignas(16) f16 lvt[64 * 32];     // v-tile transposed [dk][key]
  __shared__ alignas(16) f16 lp[4][16 * 32];   // per-wave P [qrow][key]

  // A-fragment of q, held in regs across whole key loop:
  // A[m=lane&15][k=quad*8+j]
  const int myrow = i0 + w * 16 + l15;
  const f16* qptr = qp + ((size_t)(b * 1024 + myrow)) * 1024 + h * 64;
  const f16x8 aq0 = ld8(qptr + quad * 8);        // dk 0..31
  const f16x8 aq1 = ld8(qptr + 32 + quad * 8);   // dk 32..63

  const f32x4 zero4 = {0.f, 0.f, 0.f, 0.f};
  f32x4 o[4];
  float mrun[4], lrun[4];
#pragma unroll
  for (int i = 0; i < 4; ++i) { o[i] = zero4; mrun[i] = -1e30f; lrun[i] = 0.f; }

  const int key = t >> 3, dseg = (t & 7) * 8;  // staging assignment
  const int ntiles = qt * 2 + 2;               // keys up to i0+63

  for (int jt = 0; jt < ntiles; ++jt) {
    const int j0 = jt * 32;
    __syncthreads();  // previous iter's LDS reads done
    {
      const size_t rowoff = ((size_t)(b * 1024 + j0 + key)) * 1024 + h * 64 + dseg;
      // k: byte dst = (key*64+dseg)*2 = t*16 -> contiguous, async path ok
      gld_lds16(kp + rowoff, (char*)lk + w * 1024);
      // v: transpose while staging (coalesced 16B read, 8x 2B LDS writes)
      f16x8 vv = ld8(vp + rowoff);
#pragma unroll
      for (int u = 0; u < 8; ++u) lvt[(dseg + u) * 32 + key] = vv[u];
    }
    __syncthreads();  // drains vmcnt for global_load_lds + lds writes

    // scores S[16 qrows][32 keys]: B-frag B[k=dk][n=key] from lk[key][dk]
    f32x4 sc[2];
#pragma unroll
    for (int nt = 0; nt < 2; ++nt) {
      f16x8 b0 = ld8(&lk[(nt * 16 + l15) * 64 + quad * 8]);
      f16x8 b1 = ld8(&lk[(nt * 16 + l15) * 64 + 32 + quad * 8]);
      f32x4 c = zero4;
      c = MFMA16(aq0, b0, c);
      c = MFMA16(aq1, b1, c);
      sc[nt] = c;
    }

    // mask + online softmax, per C-layout row (quad*4+rg)
#pragma unroll
    for (int rg = 0; rg < 4; ++rg) {
      const int i = i0 + w * 16 + quad * 4 + rg;
      float s0, s1;
      {
        const int d = i - (j0 + l15);
        const bool valid = (d >= 0) && ((d <= 3) || ((d & 3) == 0));
        s0 = valid ? sc[0][rg] * 0.125f : -1e30f;
      }
      {
        const int d = i - (j0 + 16 + l15);
        const bool valid = (d >= 0) && ((d <= 3) || ((d & 3) == 0));
        s1 = valid ? sc[1][rg] * 0.125f : -1e30f;
      }
      float tm = fmaxf(s0, s1);
      tm = fmaxf(tm, __shfl_xor(tm, 1));
      tm = fmaxf(tm, __shfl_xor(tm, 2));
      tm = fmaxf(tm, __shfl_xor(tm, 4));
      tm = fmaxf(tm, __shfl_xor(tm, 8));
      const float mnew = fmaxf(mrun[rg], tm);
      const float alpha = __expf(mrun[rg] - mnew);
      const float p0 = __expf(s0 - mnew);
      const float p1 = __expf(s1 - mnew);
      float ps = p0 + p1;
      ps += __shfl_xor(ps, 1);
      ps += __shfl_xor(ps, 2);
      ps += __shfl_xor(ps, 4);
      ps += __shfl_xor(ps, 8);
      lrun[rg] = lrun[rg] * alpha + ps;
      mrun[rg] = mnew;
#pragma unroll
      for (int ntv = 0; ntv < 4; ++ntv) o[ntv][rg] *= alpha;
      // P to LDS in [qrow][key] so PV A-frag is one ds_read_b128
      lp[w][(quad * 4 + rg) * 32 + l15] = (f16)p0;
      lp[w][(quad * 4 + rg) * 32 + 16 + l15] = (f16)p1;
    }
    __syncthreads();  // P visible (uniform barrier count: ntiles is block-uniform)

    // PV: A = P[m=qrow][k=key], B = V[k=key][n=dk] from lvt[dk][key]
    const f16x8 ap = ld8(&lp[w][l15 * 32 + quad * 8]);
#pragma unroll
    for (int ntv = 0; ntv < 4; ++ntv) {
      f16x8 bv = ld8(&lvt[(ntv * 16 + l15) * 32 + quad * 8]);
      o[ntv] = MFMA16(ap, bv, o[ntv]);
    }
  }

#pragma unroll
  for (int ntv = 0; ntv < 4; ++ntv) {
#pragma unroll
    for (int rg = 0; rg < 4; ++rg) {
      const int i = i0 + w * 16 + quad * 4 + rg;
      ao[((size_t)(b * 1024 + i)) * 1024 + h * 64 + ntv * 16 + l15] =
          (f16)(o[ntv][rg] / lrun[rg]);
    }
  }
}

// ---------------------------------------------------------------------------
extern "C" void kernel_launch(void* const* d_in, const int* in_sizes, int n_in,
                              void* d_out, int out_size, void* d_ws, size_t ws_size,
                              hipStream_t stream) {
  const float* Q = (const float*)d_in[0];
  const float* K = (const float*)d_in[1];
  const float* V = (const float*)d_in[2];
  const float* Wq = (const float*)d_in[3];
  const float* bq = (const float*)d_in[4];
  const float* Wk = (const float*)d_in[5];
  const float* bk = (const float*)d_in[6];
  const float* Wv = (const float*)d_in[7];
  const float* bv = (const float*)d_in[8];
  const float* Wo = (const float*)d_in[9];
  const float* bo = (const float*)d_in[10];
  float* out = (float*)d_out;

  char* ws = (char*)d_ws;
  const size_t MB = 1ull << 20;
  // [B*S, D] fp16 buffers: 8 MB each; WT: 2 MB each. Total 64 MB.
  f16* Xq = (f16*)(ws + 0 * MB);
  f16* Xk = (f16*)(ws + 8 * MB);
  f16* Xv = (f16*)(ws + 16 * MB);
  f16* TWq = (f16*)(ws + 24 * MB);
  f16* TWk = (f16*)(ws + 26 * MB);
  f16* TWv = (f16*)(ws + 28 * MB);
  f16* TWo = (f16*)(ws + 30 * MB);
  f16* qp = (f16*)(ws + 32 * MB);
  f16* kp = (f16*)(ws + 40 * MB);
  f16* vp = (f16*)(ws + 48 * MB);
  f16* ao = (f16*)(ws + 56 * MB);

  // 1) fp32 -> fp16 for Q,K,V (4096x1024 each)
  cvt_x_kernel<<<dim3(4096, 1, 3), 256, 0, stream>>>(Q, K, V, Xq, Xk, Xv);
  // 2) transpose+convert weights to [N][K] fp16
  cvt_wT_kernel<<<dim3(16, 16, 4), 256, 0, stream>>>(Wq, Wk, Wv, Wo, TWq, TWk, TWv, TWo);
  // 3) fused q/k/v projections (grid.z = which projection)
  gemm_bt_kernel<false><<<dim3(32, 8, 3), 256, 0, stream>>>(
      Xq, Xk, Xv, TWq, TWk, TWv, bq, bk, bv, qp, kp, vp, nullptr);
  // 4) sparse-masked flash attention
  attn_kernel<<<dim3(16, 16, 4), 256, 0, stream>>>(qp, kp, vp, ao);
  // 5) output projection -> fp32 d_out
  gemm_bt_kernel<true><<<dim3(32, 8, 1), 256, 0, stream>>>(
      ao, ao, ao, TWo, TWo, TWo, bo, bo, bo, nullptr, nullptr, nullptr, out);
}

// Round 2
// 274.885 us; speedup vs baseline: 1.0866x; 1.0866x over previous
//
#include <hip/hip_runtime.h>

typedef _Float16 f16;
typedef __attribute__((ext_vector_type(8))) _Float16 f16x8;
typedef __attribute__((ext_vector_type(4))) _Float16 f16x4;
typedef __attribute__((ext_vector_type(4))) float f32x4;

#define MFMA16(a, b, c) __builtin_amdgcn_mfma_f32_16x16x32_f16((a), (b), (c), 0, 0, 0)

// async global->LDS, 16B per lane. LDS base must be WAVE-UNIFORM; HW scatters
// lane i's 16B to base + i*16 (m97/m104).
__device__ __forceinline__ void gld_lds16(const void* g, void* l) {
  __builtin_amdgcn_global_load_lds(
      (__attribute__((address_space(1))) void*)const_cast<void*>(g),
      (__attribute__((address_space(3))) void*)l, 16, 0, 0);
}

__device__ __forceinline__ f16x8 ld8(const f16* p) { return *(const f16x8*)p; }

// ---------------- fp32 -> fp16 elementwise (Q,K,V) ---------------------------
__global__ __launch_bounds__(256) void cvt_x_kernel(
    const float* __restrict__ Q, const float* __restrict__ K, const float* __restrict__ V,
    f16* __restrict__ oq, f16* __restrict__ ok, f16* __restrict__ ov) {
  const float* src = blockIdx.z == 0 ? Q : (blockIdx.z == 1 ? K : V);
  f16* dst = blockIdx.z == 0 ? oq : (blockIdx.z == 1 ? ok : ov);
  size_t i = ((size_t)blockIdx.x * 256 + threadIdx.x) * 4;
  float4 f = *(const float4*)(src + i);
  f16x4 o4;
  o4.x = (f16)f.x; o4.y = (f16)f.y; o4.z = (f16)f.z; o4.w = (f16)f.w;
  *(f16x4*)(dst + i) = o4;
}

// ---------------- W [K=1024][N=1024] fp32 -> WT [N][K] fp16 ------------------
__global__ __launch_bounds__(256) void cvt_wT_kernel(
    const float* __restrict__ Wq, const float* __restrict__ Wk,
    const float* __restrict__ Wv, const float* __restrict__ Wo,
    f16* __restrict__ Tq, f16* __restrict__ Tk, f16* __restrict__ Tv, f16* __restrict__ To) {
  const int z = blockIdx.z;
  const float* W = z == 0 ? Wq : (z == 1 ? Wk : (z == 2 ? Wv : Wo));
  f16* T = z == 0 ? Tq : (z == 1 ? Tk : (z == 2 ? Tv : To));
  __shared__ float tile[64][65];
  const int k0 = blockIdx.x * 64, n0 = blockIdx.y * 64;
  const int tx = threadIdx.x & 63, ty = threadIdx.x >> 6;
#pragma unroll
  for (int rr = 0; rr < 16; ++rr) {
    int r = rr * 4 + ty;
    tile[r][tx] = W[(size_t)(k0 + r) * 1024 + n0 + tx];
  }
  __syncthreads();
#pragma unroll
  for (int rr = 0; rr < 16; ++rr) {
    int nn = rr * 4 + ty;
    T[(size_t)(n0 + nn) * 1024 + k0 + tx] = (f16)tile[tx][nn];
  }
}

// ---------------- GEMM: C[4096][1024] = A[4096][1024] * BT[1024][1024]^T + b -
// m97 structure. QKV=true: z=0,1 write per-head f16 [bh][s][64]; z=2 writes
// transposed+key-swizzled f16 vT [bh][d][swz(s)]. QKV=false: flat f32 out.
template <bool QKV>
__global__ __launch_bounds__(256) void gemm_bt_kernel(
    const f16* __restrict__ A0, const f16* __restrict__ A1, const f16* __restrict__ A2,
    const f16* __restrict__ B0, const f16* __restrict__ B1, const f16* __restrict__ B2,
    const float* __restrict__ bias0, const float* __restrict__ bias1, const float* __restrict__ bias2,
    f16* __restrict__ C0, f16* __restrict__ C1, f16* __restrict__ C2,
    float* __restrict__ Cf) {
  const int z = blockIdx.z;
  const f16* A = z == 0 ? A0 : (z == 1 ? A1 : A2);
  const f16* Bt = z == 0 ? B0 : (z == 1 ? B1 : B2);
  const float* bias = z == 0 ? bias0 : (z == 1 ? bias1 : bias2);

  __shared__ alignas(16) f16 lA[128 * 32];
  __shared__ alignas(16) f16 lB[128 * 32];

  const int t = threadIdx.x;
  const int w = t >> 6, lane = t & 63, quad = lane >> 4, l15 = lane & 15;
  const int wm = w >> 1, wn = w & 1;
  const int mbase = blockIdx.x * 128;
  const int nbase = blockIdx.y * 128;

  const f32x4 zero4 = {0.f, 0.f, 0.f, 0.f};
  f32x4 acc[4][4];
#pragma unroll
  for (int mi = 0; mi < 4; ++mi)
#pragma unroll
    for (int ni = 0; ni < 4; ++ni) acc[mi][ni] = zero4;

  const int r = t >> 2;
  const int koff = (t & 3) * 8;

  for (int k0 = 0; k0 < 1024; k0 += 32) {
    __syncthreads();
    gld_lds16(A + (size_t)(mbase + r) * 1024 + k0 + koff, (char*)lA + w * 1024);
    gld_lds16(A + (size_t)(mbase + 64 + r) * 1024 + k0 + koff, (char*)lA + 4096 + w * 1024);
    gld_lds16(Bt + (size_t)(nbase + r) * 1024 + k0 + koff, (char*)lB + w * 1024);
    gld_lds16(Bt + (size_t)(nbase + 64 + r) * 1024 + k0 + koff, (char*)lB + 4096 + w * 1024);
    __syncthreads();

    f16x8 af[4], bf[4];
#pragma unroll
    for (int mi = 0; mi < 4; ++mi)
      af[mi] = ld8(&lA[(wm * 64 + mi * 16 + l15) * 32 + quad * 8]);
#pragma unroll
    for (int ni = 0; ni < 4; ++ni)
      bf[ni] = ld8(&lB[(wn * 64 + ni * 16 + l15) * 32 + quad * 8]);
#pragma unroll
    for (int mi = 0; mi < 4; ++mi)
#pragma unroll
      for (int ni = 0; ni < 4; ++ni)
        acc[mi][ni] = MFMA16(af[mi], bf[ni], acc[mi][ni]);
  }

  // epilogue. C/D layout: col=lane&15, row=quad*4+reg (m89/m91).
#pragma unroll
  for (int mi = 0; mi < 4; ++mi) {
#pragma unroll
    for (int ni = 0; ni < 4; ++ni) {
#pragma unroll
      for (int rg = 0; rg < 4; ++rg) {
        const int row = mbase + wm * 64 + mi * 16 + quad * 4 + rg;
        const int col = nbase + wn * 64 + ni * 16 + l15;
        const float v = acc[mi][ni][rg] + bias[col];
        if (QKV) {
          const int bh = (row >> 10) * 16 + (col >> 6);
          const int s = row & 1023, d = col & 63;
          if (z != 2) {
            f16* Ch = (z == 0) ? C0 : C1;
            Ch[(size_t)bh * 65536 + s * 64 + d] = (f16)v;
          } else {
            // vT, key-swizzled within each 64-group: j -> (j&15)*4 + (j>>4)
            const int rr = s & 63;
            C2[(size_t)bh * 65536 + (size_t)d * 1024 + (s & ~63) + ((rr & 15) << 2) + (rr >> 4)] = (f16)v;
          }
        } else {
          Cf[(size_t)row * 1024 + col] = v;
        }
      }
    }
  }
}

// ---------------- flash attention, strided mask ------------------------------
// grid (8,16,4): 128 q-rows/block, 4 waves, wave w owns rows wr0..wr0+31
// (two 16-row m-tiles). Key tiles of 64. K staged [key][64] from kh (contig),
// V staged [dk][key'] from pre-transposed pre-swizzled vT (contig).
__global__ __launch_bounds__(256) void attn_kernel(
    const f16* __restrict__ qh, const f16* __restrict__ kh,
    const f16* __restrict__ vt, f16* __restrict__ ao) {
  const int qt = blockIdx.x, h = blockIdx.y, b = blockIdx.z;
  const int bh = b * 16 + h;
  const int i0 = qt * 128;
  const int t = threadIdx.x;
  const int w = t >> 6, lane = t & 63, quad = lane >> 4, l15 = lane & 15;

  __shared__ alignas(16) f16 lk[64 * 64];       // [key][dk]
  __shared__ alignas(16) f16 lvt[64 * 64];      // [dk][key'] (swizzled keys)
  __shared__ alignas(16) f16 lp[4][2][16 * 64]; // per-wave P [mt][row][key']

  const int wr0 = i0 + w * 32;
  const int wimax = wr0 + 31;

  // q A-frags in regs for the whole loop: A[m=l15][k=quad*8+j]
  const f16* qb = qh + (size_t)bh * 65536;
  f16x8 aq[2][2];
#pragma unroll
  for (int mt = 0; mt < 2; ++mt)
#pragma unroll
    for (int ko = 0; ko < 2; ++ko)
      aq[mt][ko] = ld8(qb + (size_t)(wr0 + mt * 16 + l15) * 64 + ko * 32 + quad * 8);

  const f32x4 zero4 = {0.f, 0.f, 0.f, 0.f};
  f32x4 o[2][4];
  float mrun[2][4], lrun[2][4];
#pragma unroll
  for (int mt = 0; mt < 2; ++mt)
#pragma unroll
    for (int i = 0; i < 4; ++i) {
      o[mt][i] = zero4; mrun[mt][i] = -1e30f; lrun[mt][i] = 0.f;
    }

  const f16* kb = kh + (size_t)bh * 65536;
  const f16* vb = vt + (size_t)bh * 65536;
  const float SCL2 = 0.125f * 1.44269504f;  // 1/sqrt(64) * log2(e)
  const int ntiles = 2 * qt + 2;

  for (int jt = 0; jt < ntiles; ++jt) {
    const int j0 = jt * 64;
    __syncthreads();  // previous iteration's LDS reads complete
    {
      const f16* kt = kb + (size_t)j0 * 64;     // contiguous 8 KB tile
      gld_lds16(kt + t * 8, (char*)lk + w * 1024);
      gld_lds16(kt + 2048 + t * 8, (char*)lk + 4096 + w * 1024);
      const f16* vtt = vb + j0;                 // 64 rows x 128B, stride 2KB
      gld_lds16(vtt + (size_t)(t >> 3) * 1024 + (t & 7) * 8, (char*)lvt + w * 1024);
      gld_lds16(vtt + (size_t)(32 + (t >> 3)) * 1024 + (t & 7) * 8,
                (char*)lvt + 4096 + w * 1024);
    }
    __syncthreads();  // staging visible

    if (j0 <= wimax) {  // wave-uniform causal early-out
      // ---- QK^T: B[k=dk][n=key] from lk[key][dk]
      f16x8 bk0[4], bk1[4];
#pragma unroll
      for (int nt = 0; nt < 4; ++nt) {
        bk0[nt] = ld8(&lk[(nt * 16 + l15) * 64 + quad * 8]);
        bk1[nt] = ld8(&lk[(nt * 16 + l15) * 64 + 32 + quad * 8]);
      }
#pragma unroll
      for (int mt = 0; mt < 2; ++mt) {
        f32x4 sc[4];
#pragma unroll
        for (int nt = 0; nt < 4; ++nt) {
          f32x4 c = MFMA16(aq[mt][0], bk0[nt], zero4);
          sc[nt] = MFMA16(aq[mt][1], bk1[nt], c);
        }
        // ---- mask + online softmax (base-2), C-layout row = quad*4+rg
#pragma unroll
        for (int rg = 0; rg < 4; ++rg) {
          const int i = wr0 + mt * 16 + quad * 4 + rg;
          float s[4];
#pragma unroll
          for (int nt = 0; nt < 4; ++nt) {
            const int d = i - (j0 + nt * 16 + l15);
            const bool ok = (d >= 0) && ((d <= 3) || ((d & 3) == 0));
            s[nt] = ok ? sc[nt][rg] * SCL2 : -1e30f;
          }
          float tm = fmaxf(fmaxf(s[0], s[1]), fmaxf(s[2], s[3]));
          tm = fmaxf(tm, __shfl_xor(tm, 1));
          tm = fmaxf(tm, __shfl_xor(tm, 2));
          tm = fmaxf(tm, __shfl_xor(tm, 4));
          tm = fmaxf(tm, __shfl_xor(tm, 8));
          const float mnew = fmaxf(mrun[mt][rg], tm);
          const float alpha = exp2f(mrun[mt][rg] - mnew);
          float p[4], ps = 0.f;
#pragma unroll
          for (int nt = 0; nt < 4; ++nt) { p[nt] = exp2f(s[nt] - mnew); ps += p[nt]; }
          ps += __shfl_xor(ps, 1);
          ps += __shfl_xor(ps, 2);
          ps += __shfl_xor(ps, 4);
          ps += __shfl_xor(ps, 8);
          lrun[mt][rg] = lrun[mt][rg] * alpha + ps;
          mrun[mt][rg] = mnew;
#pragma unroll
          for (int ntv = 0; ntv < 4; ++ntv) o[mt][ntv][rg] *= alpha;
          // P store, swizzled key k' = l15*4 + nt -> one 8B store, lane-contig
          f16x4 pk;
          pk.x = (f16)p[0]; pk.y = (f16)p[1]; pk.z = (f16)p[2]; pk.w = (f16)p[3];
          *(f16x4*)&lp[w][mt][(quad * 4 + rg) * 64 + l15 * 4] = pk;
        }
      }
      // ---- PV: A = P[m=row][k'=key], B = V[k'=key][n=dk] from lvt[dk][key']
      // (same-wave LDS produce->consume: lgkmcnt only, no barrier)
      f16x8 bv0[4], bv1[4];
#pragma unroll
      for (int ntv = 0; ntv < 4; ++ntv) {
        bv0[ntv] = ld8(&lvt[(ntv * 16 + l15) * 64 + quad * 8]);
        bv1[ntv] = ld8(&lvt[(ntv * 16 + l15) * 64 + 32 + quad * 8]);
      }
#pragma unroll
      for (int mt = 0; mt < 2; ++mt) {
        const f16x8 ap0 = ld8(&lp[w][mt][l15 * 64 + quad * 8]);
        const f16x8 ap1 = ld8(&lp[w][mt][l15 * 64 + 32 + quad * 8]);
#pragma unroll
        for (int ntv = 0; ntv < 4; ++ntv) {
          f32x4 c = MFMA16(ap0, bv0[ntv], o[mt][ntv]);
          o[mt][ntv] = MFMA16(ap1, bv1[ntv], c);
        }
      }
    }
  }

  // epilogue: flat [b*1024+s][1024] f16 for the out-projection GEMM
#pragma unroll
  for (int mt = 0; mt < 2; ++mt)
#pragma unroll
    for (int ntv = 0; ntv < 4; ++ntv)
#pragma unroll
      for (int rg = 0; rg < 4; ++rg) {
        const int i = wr0 + mt * 16 + quad * 4 + rg;
        ao[(size_t)(b * 1024 + i) * 1024 + h * 64 + ntv * 16 + l15] =
            (f16)(o[mt][ntv][rg] / lrun[mt][rg]);
      }
}

// ---------------------------------------------------------------------------
extern "C" void kernel_launch(void* const* d_in, const int* in_sizes, int n_in,
                              void* d_out, int out_size, void* d_ws, size_t ws_size,
                              hipStream_t stream) {
  const float* Q = (const float*)d_in[0];
  const float* K = (const float*)d_in[1];
  const float* V = (const float*)d_in[2];
  const float* Wq = (const float*)d_in[3];
  const float* bq = (const float*)d_in[4];
  const float* Wk = (const float*)d_in[5];
  const float* bk = (const float*)d_in[6];
  const float* Wv = (const float*)d_in[7];
  const float* bv = (const float*)d_in[8];
  const float* Wo = (const float*)d_in[9];
  const float* bo = (const float*)d_in[10];
  float* out = (float*)d_out;

  char* ws = (char*)d_ws;
  const size_t MB = 1ull << 20;
  f16* Xq = (f16*)(ws + 0 * MB);
  f16* Xk = (f16*)(ws + 8 * MB);
  f16* Xv = (f16*)(ws + 16 * MB);
  f16* TWq = (f16*)(ws + 24 * MB);
  f16* TWk = (f16*)(ws + 26 * MB);
  f16* TWv = (f16*)(ws + 28 * MB);
  f16* TWo = (f16*)(ws + 30 * MB);
  f16* qhb = (f16*)(ws + 32 * MB);  // [bh][s][64]
  f16* khb = (f16*)(ws + 40 * MB);  // [bh][s][64]
  f16* vtb = (f16*)(ws + 48 * MB);  // [bh][64][swz(s)]
  f16* aob = (f16*)(ws + 56 * MB);  // [b*1024+s][1024]

  cvt_x_kernel<<<dim3(4096, 1, 3), 256, 0, stream>>>(Q, K, V, Xq, Xk, Xv);
  cvt_wT_kernel<<<dim3(16, 16, 4), 256, 0, stream>>>(Wq, Wk, Wv, Wo, TWq, TWk, TWv, TWo);
  gemm_bt_kernel<true><<<dim3(32, 8, 3), 256, 0, stream>>>(
      Xq, Xk, Xv, TWq, TWk, TWv, bq, bk, bv, qhb, khb, vtb, nullptr);
  attn_kernel<<<dim3(8, 16, 4), 256, 0, stream>>>(qhb, khb, vtb, aob);
  gemm_bt_kernel<false><<<dim3(32, 8, 1), 256, 0, stream>>>(
      aob, aob, aob, TWo, TWo, TWo, bo, bo, bo, nullptr, nullptr, nullptr, out);
}

// Round 3
// 227.098 us; speedup vs baseline: 1.3153x; 1.2104x over previous
//
#include <hip/hip_runtime.h>

typedef _Float16 f16;
typedef __attribute__((ext_vector_type(8))) _Float16 f16x8;
typedef __attribute__((ext_vector_type(4))) _Float16 f16x4;
typedef __attribute__((ext_vector_type(4))) float f32x4;

#define MFMA16(a, b, c) __builtin_amdgcn_mfma_f32_16x16x32_f16((a), (b), (c), 0, 0, 0)

// async global->LDS, 16B per lane. LDS base must be WAVE-UNIFORM; HW scatters
// lane i's 16B to base + i*16 (m97/m104).
__device__ __forceinline__ void gld_lds16(const void* g, void* l) {
  __builtin_amdgcn_global_load_lds(
      (__attribute__((address_space(1))) void*)const_cast<void*>(g),
      (__attribute__((address_space(3))) void*)l, 16, 0, 0);
}

__device__ __forceinline__ f16x8 ld8(const f16* p) { return *(const f16x8*)p; }

// ---------------- fp32 -> fp16 elementwise (Q,K,V) ---------------------------
__global__ __launch_bounds__(256) void cvt_x_kernel(
    const float* __restrict__ Q, const float* __restrict__ K, const float* __restrict__ V,
    f16* __restrict__ oq, f16* __restrict__ ok, f16* __restrict__ ov) {
  const float* src = blockIdx.z == 0 ? Q : (blockIdx.z == 1 ? K : V);
  f16* dst = blockIdx.z == 0 ? oq : (blockIdx.z == 1 ? ok : ov);
  size_t i = ((size_t)blockIdx.x * 256 + threadIdx.x) * 4;
  float4 f = *(const float4*)(src + i);
  f16x4 o4;
  o4.x = (f16)f.x; o4.y = (f16)f.y; o4.z = (f16)f.z; o4.w = (f16)f.w;
  *(f16x4*)(dst + i) = o4;
}

// ---------------- W [K=1024][N=1024] fp32 -> WT [N][K] fp16 ------------------
__global__ __launch_bounds__(256) void cvt_wT_kernel(
    const float* __restrict__ Wq, const float* __restrict__ Wk,
    const float* __restrict__ Wv, const float* __restrict__ Wo,
    f16* __restrict__ Tq, f16* __restrict__ Tk, f16* __restrict__ Tv, f16* __restrict__ To) {
  const int z = blockIdx.z;
  const float* W = z == 0 ? Wq : (z == 1 ? Wk : (z == 2 ? Wv : Wo));
  f16* T = z == 0 ? Tq : (z == 1 ? Tk : (z == 2 ? Tv : To));
  __shared__ float tile[64][65];
  const int k0 = blockIdx.x * 64, n0 = blockIdx.y * 64;
  const int tx = threadIdx.x & 63, ty = threadIdx.x >> 6;
#pragma unroll
  for (int rr = 0; rr < 16; ++rr) {
    int r = rr * 4 + ty;
    tile[r][tx] = W[(size_t)(k0 + r) * 1024 + n0 + tx];
  }
  __syncthreads();
#pragma unroll
  for (int rr = 0; rr < 16; ++rr) {
    int nn = rr * 4 + ty;
    T[(size_t)(n0 + nn) * 1024 + k0 + tx] = (f16)tile[tx][nn];
  }
}

// ---------------- GEMM: C[4096][1024] = A[4096][1024] * BT[1024][1024]^T + b -
// m97 structure. QKV=true: z=0,1 write per-head f16 [bh][s][64]; z=2 writes
// plain vh [bh][s][64] AND class-gathered transposed swizzled vTg
// [bh][r=s&3][d][n=s>>2 (64-blocks swizzled)]. QKV=false: flat f32 out.
template <bool QKV>
__global__ __launch_bounds__(256) void gemm_bt_kernel(
    const f16* __restrict__ A0, const f16* __restrict__ A1, const f16* __restrict__ A2,
    const f16* __restrict__ B0, const f16* __restrict__ B1, const f16* __restrict__ B2,
    const float* __restrict__ bias0, const float* __restrict__ bias1, const float* __restrict__ bias2,
    f16* __restrict__ C0, f16* __restrict__ C1, f16* __restrict__ C2,
    f16* __restrict__ C3, float* __restrict__ Cf) {
  const int z = blockIdx.z;
  const f16* A = z == 0 ? A0 : (z == 1 ? A1 : A2);
  const f16* Bt = z == 0 ? B0 : (z == 1 ? B1 : B2);
  const float* bias = z == 0 ? bias0 : (z == 1 ? bias1 : bias2);

  __shared__ alignas(16) f16 lA[128 * 32];
  __shared__ alignas(16) f16 lB[128 * 32];

  const int t = threadIdx.x;
  const int w = t >> 6, lane = t & 63, quad = lane >> 4, l15 = lane & 15;
  const int wm = w >> 1, wn = w & 1;
  const int mbase = blockIdx.x * 128;
  const int nbase = blockIdx.y * 128;

  const f32x4 zero4 = {0.f, 0.f, 0.f, 0.f};
  f32x4 acc[4][4];
#pragma unroll
  for (int mi = 0; mi < 4; ++mi)
#pragma unroll
    for (int ni = 0; ni < 4; ++ni) acc[mi][ni] = zero4;

  const int r = t >> 2;
  const int koff = (t & 3) * 8;

  for (int k0 = 0; k0 < 1024; k0 += 32) {
    __syncthreads();
    gld_lds16(A + (size_t)(mbase + r) * 1024 + k0 + koff, (char*)lA + w * 1024);
    gld_lds16(A + (size_t)(mbase + 64 + r) * 1024 + k0 + koff, (char*)lA + 4096 + w * 1024);
    gld_lds16(Bt + (size_t)(nbase + r) * 1024 + k0 + koff, (char*)lB + w * 1024);
    gld_lds16(Bt + (size_t)(nbase + 64 + r) * 1024 + k0 + koff, (char*)lB + 4096 + w * 1024);
    __syncthreads();

    f16x8 af[4], bf[4];
#pragma unroll
    for (int mi = 0; mi < 4; ++mi)
      af[mi] = ld8(&lA[(wm * 64 + mi * 16 + l15) * 32 + quad * 8]);
#pragma unroll
    for (int ni = 0; ni < 4; ++ni)
      bf[ni] = ld8(&lB[(wn * 64 + ni * 16 + l15) * 32 + quad * 8]);
#pragma unroll
    for (int mi = 0; mi < 4; ++mi)
#pragma unroll
      for (int ni = 0; ni < 4; ++ni)
        acc[mi][ni] = MFMA16(af[mi], bf[ni], acc[mi][ni]);
  }

  // epilogue. C/D layout: col=lane&15, row=quad*4+reg (m89/m91).
#pragma unroll
  for (int mi = 0; mi < 4; ++mi) {
#pragma unroll
    for (int ni = 0; ni < 4; ++ni) {
#pragma unroll
      for (int rg = 0; rg < 4; ++rg) {
        const int row = mbase + wm * 64 + mi * 16 + quad * 4 + rg;
        const int col = nbase + wn * 64 + ni * 16 + l15;
        const float v = acc[mi][ni][rg] + bias[col];
        if (QKV) {
          const int bh = (row >> 10) * 16 + (col >> 6);
          const int s = row & 1023, d = col & 63;
          const f16 hv = (f16)v;
          if (z != 2) {
            f16* Ch = (z == 0) ? C0 : C1;
            Ch[(size_t)bh * 65536 + s * 64 + d] = hv;
          } else {
            // plain vh for the diagonal kernel
            C2[(size_t)bh * 65536 + s * 64 + d] = hv;
            // vTg: class r = s&3, class-pos n = s>>2; within 64-block swizzle
            // n -> (n&15)*4 + ((n&63)>>4) so P stores / B-frag reads vectorize.
            const int rr = s & 3, n = s >> 2, wi = n & 63;
            C3[(size_t)bh * 65536 + (size_t)rr * 16384 + (size_t)d * 256 +
               (n & ~63) + ((wi & 15) << 2) + (wi >> 4)] = hv;
          }
        } else {
          Cf[(size_t)row * 1024 + col] = v;
        }
      }
    }
  }
}

// ---------------- far-field attention (strided part: j<=i-4, (i-j)%4==0) -----
// In class space (i=4m+r, j=4n+r): pure causal n<m over 256-length sequences.
// One wave = 32 q-rows of one (bh,r); key tiles of 64 class-keys; NO barriers,
// NO staging LDS (K/V B-frags direct from global, L2-resident). Per-wave LDS
// only for the P C-layout->A-layout transpose (stride 72 kills conflicts).
// Wave-unit flattening: widx = blockIdx.x + 512*warp -> every block gets tile
// counts {1,2,3,4} = 10 units (perfect static balance).
__global__ __launch_bounds__(256) void attn_far_kernel(
    const f16* __restrict__ qh, const f16* __restrict__ kh,
    const f16* __restrict__ vtg, float* __restrict__ po, float* __restrict__ ml) {
  const int t = threadIdx.x;
  const int w = t >> 6, lane = t & 63, quad = lane >> 4, l15 = lane & 15;
  const int widx = blockIdx.x + 512 * w;
  const int bh = (widx & 255) >> 2, r = widx & 3;
  const int wq = widx >> 8;          // 0..7, 32 class-rows each
  const int m0 = wq * 32;
  const int ntiles = (wq >> 1) + 1;  // key tiles covering n < m0+32

  __shared__ alignas(16) f16 lp[4][2][16 * 72];

  const f16* qb = qh + (size_t)bh * 65536;
  const f16* kb = kh + (size_t)bh * 65536;
  const f16* vb = vtg + (size_t)bh * 65536 + (size_t)r * 16384;
  const float SCL2 = 0.125f * 1.44269504f;  // 1/sqrt(64) * log2(e)

  f16x8 aq[2][2];
#pragma unroll
  for (int mt = 0; mt < 2; ++mt) {
    const int i = 4 * (m0 + mt * 16 + l15) + r;
#pragma unroll
    for (int ko = 0; ko < 2; ++ko)
      aq[mt][ko] = ld8(qb + (size_t)i * 64 + ko * 32 + quad * 8);
  }

  const f32x4 zero4 = {0.f, 0.f, 0.f, 0.f};
  f32x4 o[2][4];
  float mrun[2][4], lrun[2][4];
#pragma unroll
  for (int mt = 0; mt < 2; ++mt)
#pragma unroll
    for (int i = 0; i < 4; ++i) {
      o[mt][i] = zero4; mrun[mt][i] = -1e30f; lrun[mt][i] = 0.f;
    }

  for (int jt = 0; jt < ntiles; ++jt) {
    const int n0 = jt * 64;
    f16x8 bk0[4], bk1[4], bv0[4], bv1[4];
#pragma unroll
    for (int nt = 0; nt < 4; ++nt) {
      const f16* kr = kb + (size_t)(4 * (n0 + nt * 16 + l15) + r) * 64;
      bk0[nt] = ld8(kr + quad * 8);
      bk1[nt] = ld8(kr + 32 + quad * 8);
      const f16* vr = vb + (size_t)(nt * 16 + l15) * 256 + n0;  // swizzled keys
      bv0[nt] = ld8(vr + quad * 8);
      bv1[nt] = ld8(vr + 32 + quad * 8);
    }
    const bool lastt = (jt == ntiles - 1);  // only tile needing the n<m mask
#pragma unroll
    for (int mt = 0; mt < 2; ++mt) {
      f32x4 sc[4];
#pragma unroll
      for (int nt = 0; nt < 4; ++nt) {
        f32x4 c = MFMA16(aq[mt][0], bk0[nt], zero4);
        sc[nt] = MFMA16(aq[mt][1], bk1[nt], c);
      }
#pragma unroll
      for (int rg = 0; rg < 4; ++rg) {
        const int m = m0 + mt * 16 + quad * 4 + rg;
        float s[4];
#pragma unroll
        for (int nt = 0; nt < 4; ++nt) {
          float vsc = sc[nt][rg] * SCL2;
          // -3e38 (not -1e30): all-masked rows (m=0) must give p==0 exactly
          if (lastt) vsc = (n0 + nt * 16 + l15 < m) ? vsc : -3.0e38f;
          s[nt] = vsc;
        }
        float tm = fmaxf(fmaxf(s[0], s[1]), fmaxf(s[2], s[3]));
        tm = fmaxf(tm, __shfl_xor(tm, 1));
        tm = fmaxf(tm, __shfl_xor(tm, 2));
        tm = fmaxf(tm, __shfl_xor(tm, 4));
        tm = fmaxf(tm, __shfl_xor(tm, 8));
        const float mnew = fmaxf(mrun[mt][rg], tm);
        const float alpha = exp2f(mrun[mt][rg] - mnew);
        float p[4], ps = 0.f;
#pragma unroll
        for (int nt = 0; nt < 4; ++nt) { p[nt] = exp2f(s[nt] - mnew); ps += p[nt]; }
        ps += __shfl_xor(ps, 1);
        ps += __shfl_xor(ps, 2);
        ps += __shfl_xor(ps, 4);
        ps += __shfl_xor(ps, 8);
        lrun[mt][rg] = lrun[mt][rg] * alpha + ps;
        mrun[mt][rg] = mnew;
#pragma unroll
        for (int ntv = 0; ntv < 4; ++ntv) o[mt][ntv][rg] *= alpha;
        // P store at swizzled key pos l15*4+nt (8B, lane-contiguous)
        f16x4 pk;
        pk.x = (f16)p[0]; pk.y = (f16)p[1]; pk.z = (f16)p[2]; pk.w = (f16)p[3];
        *(f16x4*)&lp[w][mt][(quad * 4 + rg) * 72 + l15 * 4] = pk;
      }
    }
    // PV (same-wave LDS produce->consume; compiler inserts lgkmcnt)
#pragma unroll
    for (int mt = 0; mt < 2; ++mt) {
      const f16x8 ap0 = ld8(&lp[w][mt][l15 * 72 + quad * 8]);
      const f16x8 ap1 = ld8(&lp[w][mt][l15 * 72 + 32 + quad * 8]);
#pragma unroll
      for (int ntv = 0; ntv < 4; ++ntv) {
        f32x4 c = MFMA16(ap0, bv0[ntv], o[mt][ntv]);
        o[mt][ntv] = MFMA16(ap1, bv1[ntv], c);
      }
    }
  }

  // write unnormalized partials (merged by attn_diag_kernel)
#pragma unroll
  for (int mt = 0; mt < 2; ++mt)
#pragma unroll
    for (int rg = 0; rg < 4; ++rg) {
      const int i = 4 * (m0 + mt * 16 + quad * 4 + rg) + r;
      const size_t idx = (size_t)bh * 1024 + i;
#pragma unroll
      for (int ntv = 0; ntv < 4; ++ntv)
        po[idx * 64 + ntv * 16 + l15] = o[mt][ntv][rg];
      if (l15 == 0) { ml[idx * 2] = mrun[mt][rg]; ml[idx * 2 + 1] = lrun[mt][rg]; }
    }
}

// ---------------- diagonal band (d=0..3) + merge with far partials -----------
// One wave per query; lane = dk dim. 4 dots + softmax + merge -> final ao.
__global__ __launch_bounds__(256) void attn_diag_kernel(
    const f16* __restrict__ qh, const f16* __restrict__ kh, const f16* __restrict__ vh,
    const float* __restrict__ po, const float* __restrict__ ml, f16* __restrict__ ao) {
  const int t = threadIdx.x;
  const int widx = blockIdx.x * 4 + (t >> 6);
  const int l = t & 63;
  const int bh = widx >> 10, i = widx & 1023;
  const float SCL2 = 0.125f * 1.44269504f;

  const float q = (float)qh[(size_t)bh * 65536 + (size_t)i * 64 + l];
  float s[4];
#pragma unroll
  for (int d = 0; d < 4; ++d) {
    const int j = i - d;
    const int jc = j < 0 ? 0 : j;
    float pr = q * (float)kh[(size_t)bh * 65536 + (size_t)jc * 64 + l];
    pr += __shfl_xor(pr, 1);
    pr += __shfl_xor(pr, 2);
    pr += __shfl_xor(pr, 4);
    pr += __shfl_xor(pr, 8);
    pr += __shfl_xor(pr, 16);
    pr += __shfl_xor(pr, 32);
    s[d] = (j >= 0) ? pr * SCL2 : -3.0e38f;
  }
  const float md = fmaxf(fmaxf(s[0], s[1]), fmaxf(s[2], s[3]));
  const size_t idx = (size_t)bh * 1024 + i;
  const float mf = ml[idx * 2], lf = ml[idx * 2 + 1];
  const float M = fmaxf(md, mf);
  float p[4], ld = 0.f;
#pragma unroll
  for (int d = 0; d < 4; ++d) { p[d] = exp2f(s[d] - M); ld += p[d]; }
  float ov = 0.f;
#pragma unroll
  for (int d = 0; d < 4; ++d) {
    const int jc = (i - d) < 0 ? 0 : (i - d);
    ov += p[d] * (float)vh[(size_t)bh * 65536 + (size_t)jc * 64 + l];
  }
  const float fs = exp2f(mf - M);  // mf=-1e30 (empty far set) -> 0
  const float lt = lf * fs + ld;
  const float of = po[idx * 64 + l];
  const float res = (of * fs + ov) / lt;
  const int b = bh >> 4, h = bh & 15;
  ao[((size_t)(b * 1024 + i)) * 1024 + h * 64 + l] = (f16)res;
}

// ---------------------------------------------------------------------------
extern "C" void kernel_launch(void* const* d_in, const int* in_sizes, int n_in,
                              void* d_out, int out_size, void* d_ws, size_t ws_size,
                              hipStream_t stream) {
  const float* Q = (const float*)d_in[0];
  const float* K = (const float*)d_in[1];
  const float* V = (const float*)d_in[2];
  const float* Wq = (const float*)d_in[3];
  const float* bq = (const float*)d_in[4];
  const float* Wk = (const float*)d_in[5];
  const float* bk = (const float*)d_in[6];
  const float* Wv = (const float*)d_in[7];
  const float* bv = (const float*)d_in[8];
  const float* Wo = (const float*)d_in[9];
  const float* bo = (const float*)d_in[10];
  float* out = (float*)d_out;

  char* ws = (char*)d_ws;
  const size_t MB = 1ull << 20;
  // live ranges allow overlap; total footprint 64 MB:
  f16* Xq  = (f16*)(ws + 0 * MB);    // dead after QKV gemm
  f16* Xk  = (f16*)(ws + 8 * MB);    // dead after QKV gemm
  f16* Xv  = (f16*)(ws + 16 * MB);   // dead after QKV gemm
  f16* TWq = (f16*)(ws + 24 * MB);   // dead after QKV gemm
  f16* TWk = (f16*)(ws + 26 * MB);
  f16* TWv = (f16*)(ws + 28 * MB);
  f16* TWo = (f16*)(ws + 30 * MB);   // live until out-proj
  f16* qhb = (f16*)(ws + 32 * MB);   // [bh][s][64]
  f16* khb = (f16*)(ws + 40 * MB);   // [bh][s][64]
  f16* vhb = (f16*)(ws + 48 * MB);   // [bh][s][64]
  f16* vtg = (f16*)(ws + 56 * MB);   // [bh][r][d][swz(n)]
  float* po  = (float*)(ws + 0 * MB);   // 16 MB over Xq+Xk (written post-QKV)
  float* mlb = (float*)(ws + 16 * MB);  // 0.5 MB over Xv head
  f16* aob   = (f16*)(ws + 17 * MB);    // 8 MB over Xv tail + TWq (both dead)

  cvt_x_kernel<<<dim3(4096, 1, 3), 256, 0, stream>>>(Q, K, V, Xq, Xk, Xv);
  cvt_wT_kernel<<<dim3(16, 16, 4), 256, 0, stream>>>(Wq, Wk, Wv, Wo, TWq, TWk, TWv, TWo);
  gemm_bt_kernel<true><<<dim3(32, 8, 3), 256, 0, stream>>>(
      Xq, Xk, Xv, TWq, TWk, TWv, bq, bk, bv, qhb, khb, vhb, vtg, nullptr);
  attn_far_kernel<<<dim3(512), 256, 0, stream>>>(qhb, khb, vtg, po, mlb);
  attn_diag_kernel<<<dim3(16384), 256, 0, stream>>>(qhb, khb, vhb, po, mlb, aob);
  gemm_bt_kernel<false><<<dim3(32, 8, 1), 256, 0, stream>>>(
      aob, aob, aob, TWo, TWo, TWo, bo, bo, bo, nullptr, nullptr, nullptr, nullptr, out);
}